// Round 7
// baseline (355.046 us; speedup 1.0000x reference)
//
#include <hip/hip_runtime.h>
#include <hip/hip_fp16.h>
#include <hip/hip_cooperative_groups.h>

namespace cg = cooperative_groups;

#define Hh 1024
#define Ww 1024
#define PS 1040      // padded row stride (image at offset PO)
#define PO 8         // halo offset (>= T+1)
#define T 5          // fused iterations per phase (100 = 20 phases x 5)
#define NPH 20       // phases
#define TILE 32      // output tile per block
#define R 42         // region = TILE + 2T
#define XS 44        // LDS row stride in float2 (EVEN -> 16B-aligned float4 reads)
#define NPX (R * R)  // 1764 region pixels
#define NK 7         // ceil(NPX / 256)

// packed per-pixel weights: 8 x fp16 in one 16B struct (w0..w7)
struct alignas(16) W8 { __half2 a, b, c, d; };

// ---------------------------------------------------------------------------
// prep: Ypad (luma, zero halo), x0 = b (IQ if colored else 0, zero halo),
//       x1 = 0, mask (isColored)
// ---------------------------------------------------------------------------
__global__ __launch_bounds__(256)
void prep_kernel(const float* __restrict__ gray, const float* __restrict__ app,
                 float* __restrict__ Ypad, float2* __restrict__ x0,
                 float2* __restrict__ x1, unsigned char* __restrict__ mask) {
    int px = blockIdx.x * 64 + threadIdx.x;
    int py = blockIdx.y * 4 + threadIdx.y;
    if (px >= PS || py >= PS) return;
    int p = py * PS + px;
    int i = py - PO, j = px - PO;
    float yv = 0.f;
    float2 bv = make_float2(0.f, 0.f);
    if (i >= 0 && i < Hh && j >= 0 && j < Ww) {
        int idx = i * Ww + j;
        const float s = 1.f / 255.f;
        float gr = gray[idx * 3 + 0] * s;
        float gg = gray[idx * 3 + 1] * s;
        float gb = gray[idx * 3 + 2] * s;
        float ar = app[idx * 3 + 0] * s;
        float ag = app[idx * 3 + 1] * s;
        float ab = app[idx * 3 + 2] * s;
        float diff = fabsf(gr - ar) + fabsf(gg - ag) + fabsf(gb - ab);
        bool colored = diff > 0.01f;
        yv = 0.3f * gr + 0.59f * gg + 0.11f * gb;
        float ay = 0.3f * ar + 0.59f * ag + 0.11f * ab;
        float ai = 0.74f * (ar - ay) - 0.27f * (ab - ay);
        float aq = 0.48f * (ar - ay) + 0.41f * (ab - ay);
        if (colored) bv = make_float2(ai, aq);
        mask[idx] = colored ? 1 : 0;
    }
    Ypad[p] = yv;
    x0[p] = bv;
    x1[p] = make_float2(0.f, 0.f);
}

// ---------------------------------------------------------------------------
// weights: per padded pixel, 8 normalized neighbor weights packed fp16 (16B).
// Outside the image: all zero. Colored pixel: all zero except sign bit on w0
// (-0.0h = "keep center").
// ---------------------------------------------------------------------------
__global__ __launch_bounds__(256)
void weights_kernel(const float* __restrict__ Ypad,
                    const unsigned char* __restrict__ mask,
                    W8* __restrict__ w) {
    int px = blockIdx.x * 64 + threadIdx.x;
    int py = blockIdx.y * 4 + threadIdx.y;
    if (px >= PS || py >= PS) return;
    int p = py * PS + px;
    int i = py - PO, j = px - PO;
    W8 out;
    out.a = __floats2half2_rn(0.f, 0.f);
    out.b = out.a; out.c = out.a; out.d = out.a;
    if (i >= 0 && i < Hh && j >= 0 && j < Ww) {
        float yc = Ypad[p];
        float yn[8];
        yn[0] = Ypad[p - PS - 1]; yn[1] = Ypad[p - PS]; yn[2] = Ypad[p - PS + 1];
        yn[3] = Ypad[p - 1];                            yn[4] = Ypad[p + 1];
        yn[5] = Ypad[p + PS - 1]; yn[6] = Ypad[p + PS]; yn[7] = Ypad[p + PS + 1];
        float vt = (i > 0) ? 1.f : 0.f;
        float vb = (i < Hh - 1) ? 1.f : 0.f;
        float vl = (j > 0) ? 1.f : 0.f;
        float vr = (j < Ww - 1) ? 1.f : 0.f;
        float v[8] = { vt * vl, vt, vt * vr, vl, vr, vb * vl, vb, vb * vr };

        float count = 1.f, s1 = yc;
#pragma unroll
        for (int k = 0; k < 8; ++k) { count += v[k]; s1 += v[k] * yn[k]; }
        float mean = s1 / count;
        float var = (yc - mean) * (yc - mean);
#pragma unroll
        for (int k = 0; k < 8; ++k) { float d = yn[k] - mean; var += v[k] * d * d; }
        var /= count;
        float vs = fmaxf(0.6f * var, 2e-6f);
        float inv_vs = 1.f / vs;

        float wk[8], ws = 0.f;
#pragma unroll
        for (int k = 0; k < 8; ++k) {
            float d = yn[k] - yc;
            wk[k] = v[k] * expf(-d * d * inv_vs);
            ws += wk[k];
        }
        if (mask[i * Ww + j]) {
            out.a = __floats2half2_rn(-0.0f, 0.f);  // sign bit => keep center
        } else {
            float scale = 1.f / ws;
            out.a = __floats2half2_rn(wk[0] * scale, wk[1] * scale);
            out.b = __floats2half2_rn(wk[2] * scale, wk[3] * scale);
            out.c = __floats2half2_rn(wk[4] * scale, wk[5] * scale);
            out.d = __floats2half2_rn(wk[6] * scale, wk[7] * scale);
        }
    }
    w[p] = out;
}

// unpack two adjacent pixels' packed weights to f32
__device__ inline void unpack_w(const W8& wa, const W8& wb,
                                float4& wl, float4& wh, float4& vl, float4& vh) {
    float2 a0 = __half22float2(wa.a), a1 = __half22float2(wa.b);
    float2 a2 = __half22float2(wa.c), a3 = __half22float2(wa.d);
    float2 b0 = __half22float2(wb.a), b1 = __half22float2(wb.b);
    float2 b2 = __half22float2(wb.c), b3 = __half22float2(wb.d);
    wl = make_float4(a0.x, a0.y, a1.x, a1.y);
    wh = make_float4(a2.x, a2.y, a3.x, a3.y);
    vl = make_float4(b0.x, b0.y, b1.x, b1.y);
    vh = make_float4(b2.x, b2.y, b3.x, b3.y);
}

// ---------------------------------------------------------------------------
// persist2: cooperative persistent kernel needing only 512 co-resident blocks
// (2 blocks/CU even under a 64KB-LDS-per-CU occupancy model: 29.57KB/block,
// VGPR capped by launch_bounds(256,2)). Each block owns 2 horizontally-paired
// tiles (by, 2bx) and (by, 2bx+1), processed sequentially through ONE shared
// LDS ping-pong. Per-tile stage/sweep/write is bit-identical to R5's proven
// kernel. Weights for both tiles unpacked ONCE for all 100 iterations.
// ---------------------------------------------------------------------------
__global__ __launch_bounds__(256, 2)
void persist2_kernel(float2* __restrict__ xa, float2* __restrict__ xb,
                     const W8* __restrict__ w) {
    cg::grid_group grid = cg::this_grid();
    __shared__ __align__(16) float2 xs[2][R * XS];
    int tid = threadIdx.x;
    int gi0 = blockIdx.y * TILE - T;
    int gj0t[2] = { (int)(2 * blockIdx.x) * TILE - T,
                    (int)(2 * blockIdx.x + 1) * TILE - T };

    bool active = tid < 200;
    int s  = tid / 20;
    int cp = tid - s * 20;
    int r0 = 1 + 4 * s;        // output rows r0..r0+3 (in [1,40])
    int c0 = 1 + 2 * cp;       // output cols c0, c0+1

    // load + unpack weights for BOTH tiles once (32 float4 = 128 VGPRs)
    float4 wl[2][4], wh[2][4], vl[2][4], vh[2][4];
    if (active) {
#pragma unroll
        for (int tt = 0; tt < 2; ++tt) {
#pragma unroll
            for (int i = 0; i < 4; ++i) {
                int gp = (gi0 + r0 + i + PO) * PS + (gj0t[tt] + c0 + PO);
                unpack_w(w[gp], w[gp + 1], wl[tt][i], wh[tt][i], vl[tt][i], vh[tt][i]);
            }
        }
    }

    int cur = 0;
#pragma unroll 1
    for (int phase = 0; phase < NPH; ++phase) {
        const float2* xin = (phase & 1) ? xb : xa;
        float2* xout = (phase & 1) ? xa : xb;

#pragma unroll
        for (int tt = 0; tt < 2; ++tt) {
            int gj0 = gj0t[tt];

            // full stage of this tile's region
#pragma unroll
            for (int k = 0; k < NK; ++k) {
                int pidx = tid + k * 256;
                if (pidx < NPX) {
                    int r = pidx / R, c = pidx - r * R;
                    xs[cur][r * XS + c] = xin[(gi0 + r + PO) * PS + (gj0 + c + PO)];
                }
            }
            __syncthreads();

#pragma unroll
            for (int t = 1; t <= T; ++t) {
                int nxt = cur ^ 1;
                if (active) {
                    const float4* pu = (const float4*)&xs[cur][(r0 - 1) * XS + (c0 - 1)];
                    float4 ua = pu[0], ub = pu[1];
                    const float4* pm = (const float4*)&xs[cur][r0 * XS + (c0 - 1)];
                    float4 ma = pm[0], mb = pm[1];
#pragma unroll
                    for (int i = 0; i < 4; ++i) {
                        const float4* pd = (const float4*)&xs[cur][(r0 + i + 1) * XS + (c0 - 1)];
                        float4 da = pd[0], db = pd[1];

                        // left pixel (r0+i, c0)
                        float4 lo = wl[tt][i], hi = wh[tt][i];
                        bool keep = (__float_as_uint(lo.x) >> 31) != 0u;
                        float ax = keep ? ma.z : 0.f;
                        float ay = keep ? ma.w : 0.f;
                        ax = fmaf(lo.x, ua.x, ax); ay = fmaf(lo.x, ua.y, ay);  // UL
                        ax = fmaf(lo.y, ua.z, ax); ay = fmaf(lo.y, ua.w, ay);  // U
                        ax = fmaf(lo.z, ub.x, ax); ay = fmaf(lo.z, ub.y, ay);  // UR
                        ax = fmaf(lo.w, ma.x, ax); ay = fmaf(lo.w, ma.y, ay);  // L
                        ax = fmaf(hi.x, mb.x, ax); ay = fmaf(hi.x, mb.y, ay);  // R
                        ax = fmaf(hi.y, da.x, ax); ay = fmaf(hi.y, da.y, ay);  // DL
                        ax = fmaf(hi.z, da.z, ax); ay = fmaf(hi.z, da.w, ay);  // D
                        ax = fmaf(hi.w, db.x, ax); ay = fmaf(hi.w, db.y, ay);  // DR

                        // right pixel (r0+i, c0+1)
                        float4 lo2 = vl[tt][i], hi2 = vh[tt][i];
                        bool keep2 = (__float_as_uint(lo2.x) >> 31) != 0u;
                        float bx = keep2 ? mb.x : 0.f;
                        float by = keep2 ? mb.y : 0.f;
                        bx = fmaf(lo2.x, ua.z, bx); by = fmaf(lo2.x, ua.w, by);  // UL
                        bx = fmaf(lo2.y, ub.x, bx); by = fmaf(lo2.y, ub.y, by);  // U
                        bx = fmaf(lo2.z, ub.z, bx); by = fmaf(lo2.z, ub.w, by);  // UR
                        bx = fmaf(lo2.w, ma.z, bx); by = fmaf(lo2.w, ma.w, by);  // L
                        bx = fmaf(hi2.x, mb.z, bx); by = fmaf(hi2.x, mb.w, by);  // R
                        bx = fmaf(hi2.y, da.z, bx); by = fmaf(hi2.y, da.w, by);  // DL
                        bx = fmaf(hi2.z, db.x, bx); by = fmaf(hi2.z, db.y, by);  // D
                        bx = fmaf(hi2.w, db.z, bx); by = fmaf(hi2.w, db.w, by);  // DR

                        int wp = (r0 + i) * XS + c0;
                        xs[nxt][wp]     = make_float2(ax, ay);
                        xs[nxt][wp + 1] = make_float2(bx, by);

                        ua = ma; ub = mb; ma = da; mb = db;  // slide window
                    }
                }
                __syncthreads();
                cur = nxt;
            }

            // write central 32x32 tile (region rows/cols 5..36)
#pragma unroll
            for (int k = 0; k < 4; ++k) {
                int pidx = tid + k * 256;
                int r = T + (pidx >> 5), c = T + (pidx & 31);
                xout[(gi0 + r + PO) * PS + (gj0 + c + PO)] = xs[cur][r * XS + c];
            }
            __syncthreads();  // protect xs[cur] until writes land, before next tile clobbers
        }

        __threadfence();   // device-scope release of tile writes
        grid.sync();
        __threadfence();   // acquire side
    }
}

// ---------------------------------------------------------------------------
// iter5 (FALLBACK, proven R5 kernel): one 5-sweep launch.
// ---------------------------------------------------------------------------
__global__ __launch_bounds__(256, 4)
void iter5_kernel(const float2* __restrict__ xin, float2* __restrict__ xout,
                  const W8* __restrict__ w) {
    __shared__ __align__(16) float2 xs[2][R * XS];
    int tid = threadIdx.x;
    int gi0 = blockIdx.y * TILE - T;
    int gj0 = blockIdx.x * TILE - T;

#pragma unroll
    for (int k = 0; k < NK; ++k) {
        int pidx = tid + k * 256;
        if (pidx < NPX) {
            int r = pidx / R, c = pidx - r * R;
            int gp = (gi0 + r + PO) * PS + (gj0 + c + PO);
            xs[0][r * XS + c] = xin[gp];
        }
    }

    bool active = tid < 200;
    int s  = tid / 20;
    int cp = tid - s * 20;
    int r0 = 1 + 4 * s;
    int c0 = 1 + 2 * cp;

    float4 wl[4], wh[4], vl[4], vh[4];
    if (active) {
#pragma unroll
        for (int i = 0; i < 4; ++i) {
            int gp = (gi0 + r0 + i + PO) * PS + (gj0 + c0 + PO);
            unpack_w(w[gp], w[gp + 1], wl[i], wh[i], vl[i], vh[i]);
        }
    }
    __syncthreads();

    int cur = 0;
#pragma unroll
    for (int t = 1; t <= T; ++t) {
        int nxt = cur ^ 1;
        if (active) {
            const float4* pu = (const float4*)&xs[cur][(r0 - 1) * XS + (c0 - 1)];
            float4 ua = pu[0], ub = pu[1];
            const float4* pm = (const float4*)&xs[cur][r0 * XS + (c0 - 1)];
            float4 ma = pm[0], mb = pm[1];
#pragma unroll
            for (int i = 0; i < 4; ++i) {
                const float4* pd = (const float4*)&xs[cur][(r0 + i + 1) * XS + (c0 - 1)];
                float4 da = pd[0], db = pd[1];

                float4 lo = wl[i], hi = wh[i];
                bool keep = (__float_as_uint(lo.x) >> 31) != 0u;
                float ax = keep ? ma.z : 0.f;
                float ay = keep ? ma.w : 0.f;
                ax = fmaf(lo.x, ua.x, ax); ay = fmaf(lo.x, ua.y, ay);
                ax = fmaf(lo.y, ua.z, ax); ay = fmaf(lo.y, ua.w, ay);
                ax = fmaf(lo.z, ub.x, ax); ay = fmaf(lo.z, ub.y, ay);
                ax = fmaf(lo.w, ma.x, ax); ay = fmaf(lo.w, ma.y, ay);
                ax = fmaf(hi.x, mb.x, ax); ay = fmaf(hi.x, mb.y, ay);
                ax = fmaf(hi.y, da.x, ax); ay = fmaf(hi.y, da.y, ay);
                ax = fmaf(hi.z, da.z, ax); ay = fmaf(hi.z, da.w, ay);
                ax = fmaf(hi.w, db.x, ax); ay = fmaf(hi.w, db.y, ay);

                float4 lo2 = vl[i], hi2 = vh[i];
                bool keep2 = (__float_as_uint(lo2.x) >> 31) != 0u;
                float bx = keep2 ? mb.x : 0.f;
                float by = keep2 ? mb.y : 0.f;
                bx = fmaf(lo2.x, ua.z, bx); by = fmaf(lo2.x, ua.w, by);
                bx = fmaf(lo2.y, ub.x, bx); by = fmaf(lo2.y, ub.y, by);
                bx = fmaf(lo2.z, ub.z, bx); by = fmaf(lo2.z, ub.w, by);
                bx = fmaf(lo2.w, ma.z, bx); by = fmaf(lo2.w, ma.w, by);
                bx = fmaf(hi2.x, mb.z, bx); by = fmaf(hi2.x, mb.w, by);
                bx = fmaf(hi2.y, da.z, bx); by = fmaf(hi2.y, da.w, by);
                bx = fmaf(hi2.z, db.x, bx); by = fmaf(hi2.z, db.y, by);
                bx = fmaf(hi2.w, db.z, bx); by = fmaf(hi2.w, db.w, by);

                int wp = (r0 + i) * XS + c0;
                xs[nxt][wp]     = make_float2(ax, ay);
                xs[nxt][wp + 1] = make_float2(bx, by);

                ua = ma; ub = mb; ma = da; mb = db;
            }
        }
        __syncthreads();
        cur = nxt;
    }

#pragma unroll
    for (int k = 0; k < 4; ++k) {
        int pidx = tid + k * 256;
        int r = T + (pidx >> 5), c = T + (pidx & 31);
        int gp = (gi0 + r + PO) * PS + (gj0 + c + PO);
        xout[gp] = xs[cur][r * XS + c];
    }
}

// ---------------------------------------------------------------------------
// final: yiq -> rgb, clip, *255
// ---------------------------------------------------------------------------
__global__ __launch_bounds__(256)
void final_kernel(const float* __restrict__ Ypad, const float2* __restrict__ x,
                  float* __restrict__ out) {
    int j = blockIdx.x * 64 + threadIdx.x;
    int i = blockIdx.y * 4 + threadIdx.y;
    int idx = i * Ww + j;
    int p = (i + PO) * PS + (j + PO);
    float y = Ypad[p];
    float2 iq = x[p];
    float R_ = y + 0.9468822170900693f * iq.x + 0.6235565819861433f * iq.y;
    float G_ = y - 0.27478764629897834f * iq.x - 0.6356910791873801f * iq.y;
    float B_ = y - 1.1085450346420322f * iq.x + 1.7090069284064666f * iq.y;
    out[idx * 3 + 0] = fminf(fmaxf(R_, 0.f), 1.f) * 255.f;
    out[idx * 3 + 1] = fminf(fmaxf(G_, 0.f), 1.f) * 255.f;
    out[idx * 3 + 2] = fminf(fmaxf(B_, 0.f), 1.f) * 255.f;
}

extern "C" void kernel_launch(void* const* d_in, const int* in_sizes, int n_in,
                              void* d_out, int out_size, void* d_ws, size_t ws_size,
                              hipStream_t stream) {
    const float* gray = (const float*)d_in[0];
    const float* app  = (const float*)d_in[1];
    float* out = (float*)d_out;

    char* ws = (char*)d_ws;
    size_t off = 0;
    auto alloc = [&](size_t bytes) -> void* {
        void* r = ws + off;
        off = (off + bytes + 255) & ~(size_t)255;
        return r;
    };
    float*  Ypad = (float*) alloc((size_t)PS * PS * sizeof(float));
    W8*     w    = (W8*)    alloc((size_t)PS * PS * sizeof(W8));
    unsigned char* mask = (unsigned char*)alloc((size_t)Hh * Ww);
    float2* x0   = (float2*)alloc((size_t)PS * PS * sizeof(float2));
    float2* x1   = (float2*)alloc((size_t)PS * PS * sizeof(float2));

    dim3 blk(64, 4);
    dim3 gridPad((PS + 63) / 64, (PS + 3) / 4);
    prep_kernel<<<gridPad, blk, 0, stream>>>(gray, app, Ypad, x0, x1, mask);
    weights_kernel<<<gridPad, blk, 0, stream>>>(Ypad, mask, w);

    // Can 512 cooperative blocks be co-resident? (host-side queries, capture-safe)
    int dev = 0;
    (void)hipGetDevice(&dev);
    int nCU = 0;
    (void)hipDeviceGetAttribute(&nCU, hipDeviceAttributeMultiprocessorCount, dev);
    int maxBlk = 0;
    (void)hipOccupancyMaxActiveBlocksPerMultiprocessor(&maxBlk, persist2_kernel, 256, 0);
    bool coop = (nCU > 0) && ((long)maxBlk * nCU >= 512);

    if (coop) {
        float2* a0 = x0;
        float2* a1 = x1;
        const W8* a2 = w;
        void* args[] = { (void*)&a0, (void*)&a1, (void*)&a2 };
        hipError_t e = hipLaunchCooperativeKernel(persist2_kernel,
                                                  dim3(16, 32), dim3(256),
                                                  args, 0, stream);
        if (e != hipSuccess) coop = false;   // deterministic per-device: same path every call
    }
    if (!coop) {
        // proven R5 path: 20 launches x 5 fused iterations
        dim3 gridIter(Ww / TILE, Hh / TILE);
        float2* xin = x0;
        float2* xout = x1;
        for (int l = 0; l < 20; ++l) {
            iter5_kernel<<<gridIter, 256, 0, stream>>>(xin, xout, w);
            float2* tmp = xin; xin = xout; xout = tmp;
        }
    }

    // both paths end with the 100-iteration state in x0
    dim3 gridImg(Ww / 64, Hh / 4);
    final_kernel<<<gridImg, blk, 0, stream>>>(Ypad, x0, out);
}

// Round 8
// 340.478 us; speedup vs baseline: 1.0428x; 1.0428x over previous
//
#include <hip/hip_runtime.h>
#include <hip/hip_fp16.h>

#define Hh 1024
#define Ww 1024
#define PS 1040      // padded row stride (image at offset PO)
#define PO 8         // halo offset (>= T+1)
#define T 5          // fused iterations per launch (100 = 20 launches x 5)
#define TILE 32      // output tile per block
#define R 42         // region = TILE + 2T
#define XSH 44       // LDS row stride in px (half2 = 4B each; EVEN -> uint2 reads aligned)
#define NPX (R * R)  // 1764 region pixels
#define NK 7         // ceil(NPX / 256)

typedef unsigned int u32;

// packed per-pixel weights: 8 x fp16 in one 16B struct (w0..w7)
struct alignas(16) W8 { __half2 a, b, c, d; };

// ---------------------------------------------------------------------------
// prep: Ypad (luma, zero halo), x0 = b as half2 (IQ if colored else 0, zero
// halo), x1 = 0, mask (isColored). x state is fp16 everywhere: it passes
// through fp16 LDS every sweep anyway, so fp16 global storage adds no error.
// ---------------------------------------------------------------------------
__global__ __launch_bounds__(256)
void prep_kernel(const float* __restrict__ gray, const float* __restrict__ app,
                 float* __restrict__ Ypad, u32* __restrict__ x0,
                 u32* __restrict__ x1, unsigned char* __restrict__ mask) {
    int px = blockIdx.x * 64 + threadIdx.x;
    int py = blockIdx.y * 4 + threadIdx.y;
    if (px >= PS || py >= PS) return;
    int p = py * PS + px;
    int i = py - PO, j = px - PO;
    float yv = 0.f;
    float2 bv = make_float2(0.f, 0.f);
    if (i >= 0 && i < Hh && j >= 0 && j < Ww) {
        int idx = i * Ww + j;
        const float s = 1.f / 255.f;
        float gr = gray[idx * 3 + 0] * s;
        float gg = gray[idx * 3 + 1] * s;
        float gb = gray[idx * 3 + 2] * s;
        float ar = app[idx * 3 + 0] * s;
        float ag = app[idx * 3 + 1] * s;
        float ab = app[idx * 3 + 2] * s;
        float diff = fabsf(gr - ar) + fabsf(gg - ag) + fabsf(gb - ab);
        bool colored = diff > 0.01f;
        yv = 0.3f * gr + 0.59f * gg + 0.11f * gb;
        float ay = 0.3f * ar + 0.59f * ag + 0.11f * ab;
        float ai = 0.74f * (ar - ay) - 0.27f * (ab - ay);
        float aq = 0.48f * (ar - ay) + 0.41f * (ab - ay);
        if (colored) bv = make_float2(ai, aq);
        mask[idx] = colored ? 1 : 0;
    }
    Ypad[p] = yv;
    __half2 h = __floats2half2_rn(bv.x, bv.y);
    x0[p] = *(u32*)&h;
    x1[p] = 0u;                 // half2(0,0)
}

// ---------------------------------------------------------------------------
// weights: per padded pixel, 8 normalized neighbor weights packed fp16 (16B).
// Outside the image: all zero. Colored pixel: all zero except sign bit on w0
// (-0.0h = "keep center").
// ---------------------------------------------------------------------------
__global__ __launch_bounds__(256)
void weights_kernel(const float* __restrict__ Ypad,
                    const unsigned char* __restrict__ mask,
                    W8* __restrict__ w) {
    int px = blockIdx.x * 64 + threadIdx.x;
    int py = blockIdx.y * 4 + threadIdx.y;
    if (px >= PS || py >= PS) return;
    int p = py * PS + px;
    int i = py - PO, j = px - PO;
    W8 out;
    out.a = __floats2half2_rn(0.f, 0.f);
    out.b = out.a; out.c = out.a; out.d = out.a;
    if (i >= 0 && i < Hh && j >= 0 && j < Ww) {
        float yc = Ypad[p];
        float yn[8];
        yn[0] = Ypad[p - PS - 1]; yn[1] = Ypad[p - PS]; yn[2] = Ypad[p - PS + 1];
        yn[3] = Ypad[p - 1];                            yn[4] = Ypad[p + 1];
        yn[5] = Ypad[p + PS - 1]; yn[6] = Ypad[p + PS]; yn[7] = Ypad[p + PS + 1];
        float vt = (i > 0) ? 1.f : 0.f;
        float vb = (i < Hh - 1) ? 1.f : 0.f;
        float vl = (j > 0) ? 1.f : 0.f;
        float vr = (j < Ww - 1) ? 1.f : 0.f;
        float v[8] = { vt * vl, vt, vt * vr, vl, vr, vb * vl, vb, vb * vr };

        float count = 1.f, s1 = yc;
#pragma unroll
        for (int k = 0; k < 8; ++k) { count += v[k]; s1 += v[k] * yn[k]; }
        float mean = s1 / count;
        float var = (yc - mean) * (yc - mean);
#pragma unroll
        for (int k = 0; k < 8; ++k) { float d = yn[k] - mean; var += v[k] * d * d; }
        var /= count;
        float vs = fmaxf(0.6f * var, 2e-6f);
        float inv_vs = 1.f / vs;

        float wk[8], ws = 0.f;
#pragma unroll
        for (int k = 0; k < 8; ++k) {
            float d = yn[k] - yc;
            wk[k] = v[k] * expf(-d * d * inv_vs);
            ws += wk[k];
        }
        if (mask[i * Ww + j]) {
            out.a = __floats2half2_rn(-0.0f, 0.f);  // sign bit => keep center
        } else {
            float scale = 1.f / ws;
            out.a = __floats2half2_rn(wk[0] * scale, wk[1] * scale);
            out.b = __floats2half2_rn(wk[2] * scale, wk[3] * scale);
            out.c = __floats2half2_rn(wk[4] * scale, wk[5] * scale);
            out.d = __floats2half2_rn(wk[6] * scale, wk[7] * scale);
        }
    }
    w[p] = out;
}

// unpack two adjacent pixels' packed weights to f32
__device__ inline void unpack_w(const W8& wa, const W8& wb,
                                float4& wl, float4& wh, float4& vl, float4& vh) {
    float2 a0 = __half22float2(wa.a), a1 = __half22float2(wa.b);
    float2 a2 = __half22float2(wa.c), a3 = __half22float2(wa.d);
    float2 b0 = __half22float2(wb.a), b1 = __half22float2(wb.b);
    float2 b2 = __half22float2(wb.c), b3 = __half22float2(wb.d);
    wl = make_float4(a0.x, a0.y, a1.x, a1.y);
    wh = make_float4(a2.x, a2.y, a3.x, a3.y);
    vl = make_float4(b0.x, b0.y, b1.x, b1.y);
    vh = make_float4(b2.x, b2.y, b3.x, b3.y);
}

// read 4 consecutive px (c0-1..c0+2, even-aligned) from a half2 LDS row into
// two float4s matching the R5 window layout (x/y = px0 IQ, z/w = px1 IQ, ...)
__device__ inline void load_row(const u32* rowbase, int cp, float4& A, float4& B) {
    const uint2* rp = (const uint2*)rowbase;       // row start even-aligned
    uint2 p0 = rp[cp];                             // px c0-1, c0
    uint2 p1 = rp[cp + 1];                         // px c0+1, c0+2
    float2 f0 = __half22float2(*(const __half2*)&p0.x);
    float2 f1 = __half22float2(*(const __half2*)&p0.y);
    float2 f2 = __half22float2(*(const __half2*)&p1.x);
    float2 f3 = __half22float2(*(const __half2*)&p1.y);
    A = make_float4(f0.x, f0.y, f1.x, f1.y);
    B = make_float4(f2.x, f2.y, f3.x, f3.y);
}

// ---------------------------------------------------------------------------
// iter5h: temporal-tiled register-window stencil with fp16 x-state in LDS.
// Per thread per sweep: 12 ds_read_b64 + 8 ds_write_b32 (= 120 LDS cyc vs 192
// for fp32 state). Math in fp32 (convert on load, RN on store) -> same op
// order as R5; state quantized to fp16 once per sweep.
// writeRGB!=0 (last launch): fused epilogue writes RGB directly (no xout, no
// separate final kernel).
// ---------------------------------------------------------------------------
__global__ __launch_bounds__(256, 4)
void iter5h_kernel(const u32* __restrict__ xin, u32* __restrict__ xout,
                   const W8* __restrict__ w, const float* __restrict__ Ypad,
                   float* __restrict__ out, int writeRGB) {
    __shared__ __align__(16) u32 xsm[2][R * XSH];
    int tid = threadIdx.x;
    int gi0 = blockIdx.y * TILE - T;
    int gj0 = blockIdx.x * TILE - T;

    // stage x region (half2 px = b32 loads/stores)
#pragma unroll
    for (int k = 0; k < NK; ++k) {
        int pidx = tid + k * 256;
        if (pidx < NPX) {
            int r = pidx / R, c = pidx - r * R;
            xsm[0][r * XSH + c] = xin[(gi0 + r + PO) * PS + (gj0 + c + PO)];
        }
    }

    bool active = tid < 200;
    int s  = tid / 20;
    int cp = tid - s * 20;
    int r0 = 1 + 4 * s;        // output rows r0..r0+3 (in [1,40])
    int c0 = 1 + 2 * cp;       // output cols c0, c0+1 (c0-1 = 2cp even)

    float4 wl[4], wh[4], vl[4], vh[4];
    if (active) {
#pragma unroll
        for (int i = 0; i < 4; ++i) {
            int gp = (gi0 + r0 + i + PO) * PS + (gj0 + c0 + PO);
            unpack_w(w[gp], w[gp + 1], wl[i], wh[i], vl[i], vh[i]);
        }
    }
    __syncthreads();

    int cur = 0;
#pragma unroll
    for (int t = 1; t <= T; ++t) {
        int nxt = cur ^ 1;
        if (active) {
            float4 ua, ub, ma, mb;
            load_row(&xsm[cur][(r0 - 1) * XSH], cp, ua, ub);
            load_row(&xsm[cur][r0 * XSH], cp, ma, mb);
#pragma unroll
            for (int i = 0; i < 4; ++i) {
                float4 da, db;
                load_row(&xsm[cur][(r0 + i + 1) * XSH], cp, da, db);

                // left pixel (r0+i, c0)
                float4 lo = wl[i], hi = wh[i];
                bool keep = (__float_as_uint(lo.x) >> 31) != 0u;
                float ax = keep ? ma.z : 0.f;
                float ay = keep ? ma.w : 0.f;
                ax = fmaf(lo.x, ua.x, ax); ay = fmaf(lo.x, ua.y, ay);  // UL
                ax = fmaf(lo.y, ua.z, ax); ay = fmaf(lo.y, ua.w, ay);  // U
                ax = fmaf(lo.z, ub.x, ax); ay = fmaf(lo.z, ub.y, ay);  // UR
                ax = fmaf(lo.w, ma.x, ax); ay = fmaf(lo.w, ma.y, ay);  // L
                ax = fmaf(hi.x, mb.x, ax); ay = fmaf(hi.x, mb.y, ay);  // R
                ax = fmaf(hi.y, da.x, ax); ay = fmaf(hi.y, da.y, ay);  // DL
                ax = fmaf(hi.z, da.z, ax); ay = fmaf(hi.z, da.w, ay);  // D
                ax = fmaf(hi.w, db.x, ax); ay = fmaf(hi.w, db.y, ay);  // DR

                // right pixel (r0+i, c0+1)
                float4 lo2 = vl[i], hi2 = vh[i];
                bool keep2 = (__float_as_uint(lo2.x) >> 31) != 0u;
                float bx = keep2 ? mb.x : 0.f;
                float by = keep2 ? mb.y : 0.f;
                bx = fmaf(lo2.x, ua.z, bx); by = fmaf(lo2.x, ua.w, by);  // UL
                bx = fmaf(lo2.y, ub.x, bx); by = fmaf(lo2.y, ub.y, by);  // U
                bx = fmaf(lo2.z, ub.z, bx); by = fmaf(lo2.z, ub.w, by);  // UR
                bx = fmaf(lo2.w, ma.z, bx); by = fmaf(lo2.w, ma.w, by);  // L
                bx = fmaf(hi2.x, mb.z, bx); by = fmaf(hi2.x, mb.w, by);  // R
                bx = fmaf(hi2.y, da.z, bx); by = fmaf(hi2.y, da.w, by);  // DL
                bx = fmaf(hi2.z, db.x, bx); by = fmaf(hi2.z, db.y, by);  // D
                bx = fmaf(hi2.w, db.z, bx); by = fmaf(hi2.w, db.w, by);  // DR

                __half2 h0 = __floats2half2_rn(ax, ay);
                __half2 h1 = __floats2half2_rn(bx, by);
                int wp = (r0 + i) * XSH + c0;
                xsm[nxt][wp]     = *(u32*)&h0;
                xsm[nxt][wp + 1] = *(u32*)&h1;

                ua = ma; ub = mb; ma = da; mb = db;  // slide window
            }
        }
        __syncthreads();
        cur = nxt;
    }

    if (!writeRGB) {
        // write central 32x32 tile (region rows/cols 5..36) as half2
#pragma unroll
        for (int k = 0; k < 4; ++k) {
            int pidx = tid + k * 256;
            int r = T + (pidx >> 5), c = T + (pidx & 31);
            xout[(gi0 + r + PO) * PS + (gj0 + c + PO)] = xsm[cur][r * XSH + c];
        }
    } else {
        // fused final: yiq -> rgb, clip, *255 straight from LDS
#pragma unroll
        for (int k = 0; k < 4; ++k) {
            int pidx = tid + k * 256;
            int r = T + (pidx >> 5), c = T + (pidx & 31);
            int gi = gi0 + r, gj = gj0 + c;
            float y = Ypad[(gi + PO) * PS + (gj + PO)];
            u32 pxv = xsm[cur][r * XSH + c];
            float2 iq = __half22float2(*(const __half2*)&pxv);
            float R_ = y + 0.9468822170900693f * iq.x + 0.6235565819861433f * iq.y;
            float G_ = y - 0.27478764629897834f * iq.x - 0.6356910791873801f * iq.y;
            float B_ = y - 1.1085450346420322f * iq.x + 1.7090069284064666f * iq.y;
            int idx = gi * Ww + gj;
            out[idx * 3 + 0] = fminf(fmaxf(R_, 0.f), 1.f) * 255.f;
            out[idx * 3 + 1] = fminf(fmaxf(G_, 0.f), 1.f) * 255.f;
            out[idx * 3 + 2] = fminf(fmaxf(B_, 0.f), 1.f) * 255.f;
        }
    }
}

extern "C" void kernel_launch(void* const* d_in, const int* in_sizes, int n_in,
                              void* d_out, int out_size, void* d_ws, size_t ws_size,
                              hipStream_t stream) {
    const float* gray = (const float*)d_in[0];
    const float* app  = (const float*)d_in[1];
    float* out = (float*)d_out;

    char* ws = (char*)d_ws;
    size_t off = 0;
    auto alloc = [&](size_t bytes) -> void* {
        void* r = ws + off;
        off = (off + bytes + 255) & ~(size_t)255;
        return r;
    };
    float* Ypad = (float*)alloc((size_t)PS * PS * sizeof(float));
    W8*    w    = (W8*)   alloc((size_t)PS * PS * sizeof(W8));
    unsigned char* mask = (unsigned char*)alloc((size_t)Hh * Ww);
    u32*   x0   = (u32*)  alloc((size_t)PS * PS * sizeof(u32));
    u32*   x1   = (u32*)  alloc((size_t)PS * PS * sizeof(u32));

    dim3 blk(64, 4);
    dim3 gridPad((PS + 63) / 64, (PS + 3) / 4);
    prep_kernel<<<gridPad, blk, 0, stream>>>(gray, app, Ypad, x0, x1, mask);
    weights_kernel<<<gridPad, blk, 0, stream>>>(Ypad, mask, w);

    dim3 gridIter(Ww / TILE, Hh / TILE);  // 32 x 32 = 1024 blocks
    u32* xin = x0;
    u32* xout = x1;
    for (int l = 0; l < 20; ++l) {        // 20 x 5 = 100 iterations
        int last = (l == 19) ? 1 : 0;
        iter5h_kernel<<<gridIter, 256, 0, stream>>>(xin, xout, w, Ypad, out, last);
        u32* tmp = xin; xin = xout; xout = tmp;
    }
}

// Round 9
// 309.960 us; speedup vs baseline: 1.1455x; 1.0985x over previous
//
#include <hip/hip_runtime.h>
#include <hip/hip_fp16.h>

#define Hh 1024
#define Ww 1024
#define PS 1040      // padded row stride (image at offset PO)
#define PO 8         // halo offset (>= T+1)
#define T 5          // fused iterations per launch (100 = 20 launches x 5)
#define TILE 32      // output tile per block
#define R 42         // region = TILE + 2T
#define XSH 44       // LDS row stride in px (half2 = 4B each; EVEN -> uint2 reads aligned)
#define NPX (R * R)  // 1764 region pixels
#define NK 7         // ceil(NPX / 256)

typedef unsigned int u32;

// packed per-pixel weights: 8 x fp16 in one 16B struct (w0..w7)
struct alignas(16) W8 { __half2 a, b, c, d; };

__device__ inline __half2 h2(u32 v) { return *(__half2*)&v; }
__device__ inline u32 u2(__half2 v) { return *(u32*)&v; }

// ---------------------------------------------------------------------------
// prep: Ypad (luma, zero halo), x0 = b as half2 (IQ if colored else 0, zero
// halo), x1 = 0, mask (isColored).
// ---------------------------------------------------------------------------
__global__ __launch_bounds__(256)
void prep_kernel(const float* __restrict__ gray, const float* __restrict__ app,
                 float* __restrict__ Ypad, u32* __restrict__ x0,
                 u32* __restrict__ x1, unsigned char* __restrict__ mask) {
    int px = blockIdx.x * 64 + threadIdx.x;
    int py = blockIdx.y * 4 + threadIdx.y;
    if (px >= PS || py >= PS) return;
    int p = py * PS + px;
    int i = py - PO, j = px - PO;
    float yv = 0.f;
    float2 bv = make_float2(0.f, 0.f);
    if (i >= 0 && i < Hh && j >= 0 && j < Ww) {
        int idx = i * Ww + j;
        const float s = 1.f / 255.f;
        float gr = gray[idx * 3 + 0] * s;
        float gg = gray[idx * 3 + 1] * s;
        float gb = gray[idx * 3 + 2] * s;
        float ar = app[idx * 3 + 0] * s;
        float ag = app[idx * 3 + 1] * s;
        float ab = app[idx * 3 + 2] * s;
        float diff = fabsf(gr - ar) + fabsf(gg - ag) + fabsf(gb - ab);
        bool colored = diff > 0.01f;
        yv = 0.3f * gr + 0.59f * gg + 0.11f * gb;
        float ay = 0.3f * ar + 0.59f * ag + 0.11f * ab;
        float ai = 0.74f * (ar - ay) - 0.27f * (ab - ay);
        float aq = 0.48f * (ar - ay) + 0.41f * (ab - ay);
        if (colored) bv = make_float2(ai, aq);
        mask[idx] = colored ? 1 : 0;
    }
    Ypad[p] = yv;
    __half2 h = __floats2half2_rn(bv.x, bv.y);
    x0[p] = u2(h);
    x1[p] = 0u;                 // half2(0,0)
}

// ---------------------------------------------------------------------------
// weights: per padded pixel, 8 normalized neighbor weights packed fp16 (16B).
// Outside the image: all zero. Colored pixel: all zero except sign bit on w0
// (-0.0h = "keep center").
// ---------------------------------------------------------------------------
__global__ __launch_bounds__(256)
void weights_kernel(const float* __restrict__ Ypad,
                    const unsigned char* __restrict__ mask,
                    W8* __restrict__ w) {
    int px = blockIdx.x * 64 + threadIdx.x;
    int py = blockIdx.y * 4 + threadIdx.y;
    if (px >= PS || py >= PS) return;
    int p = py * PS + px;
    int i = py - PO, j = px - PO;
    W8 out;
    out.a = __floats2half2_rn(0.f, 0.f);
    out.b = out.a; out.c = out.a; out.d = out.a;
    if (i >= 0 && i < Hh && j >= 0 && j < Ww) {
        float yc = Ypad[p];
        float yn[8];
        yn[0] = Ypad[p - PS - 1]; yn[1] = Ypad[p - PS]; yn[2] = Ypad[p - PS + 1];
        yn[3] = Ypad[p - 1];                            yn[4] = Ypad[p + 1];
        yn[5] = Ypad[p + PS - 1]; yn[6] = Ypad[p + PS]; yn[7] = Ypad[p + PS + 1];
        float vt = (i > 0) ? 1.f : 0.f;
        float vb = (i < Hh - 1) ? 1.f : 0.f;
        float vl = (j > 0) ? 1.f : 0.f;
        float vr = (j < Ww - 1) ? 1.f : 0.f;
        float v[8] = { vt * vl, vt, vt * vr, vl, vr, vb * vl, vb, vb * vr };

        float count = 1.f, s1 = yc;
#pragma unroll
        for (int k = 0; k < 8; ++k) { count += v[k]; s1 += v[k] * yn[k]; }
        float mean = s1 / count;
        float var = (yc - mean) * (yc - mean);
#pragma unroll
        for (int k = 0; k < 8; ++k) { float d = yn[k] - mean; var += v[k] * d * d; }
        var /= count;
        float vs = fmaxf(0.6f * var, 2e-6f);
        float inv_vs = 1.f / vs;

        float wk[8], ws = 0.f;
#pragma unroll
        for (int k = 0; k < 8; ++k) {
            float d = yn[k] - yc;
            wk[k] = v[k] * expf(-d * d * inv_vs);
            ws += wk[k];
        }
        if (mask[i * Ww + j]) {
            out.a = __floats2half2_rn(-0.0f, 0.f);  // sign bit => keep center
        } else {
            float scale = 1.f / ws;
            out.a = __floats2half2_rn(wk[0] * scale, wk[1] * scale);
            out.b = __floats2half2_rn(wk[2] * scale, wk[3] * scale);
            out.c = __floats2half2_rn(wk[4] * scale, wk[5] * scale);
            out.d = __floats2half2_rn(wk[6] * scale, wk[7] * scale);
        }
    }
    w[p] = out;
}

// ---------------------------------------------------------------------------
// iter5p: temporal-tiled register-window stencil, PACKED fp16 math.
// State (I,Q) lives as half2 end-to-end: LDS b64 reads feed v_pk_fma_f16
// directly (zero converts), stores are raw u32. Weights duplicated to
// half2(w,w) registers once per launch. 8 hfma2/px vs 16 fma + ~6 cvt before.
// writeRGB!=0 (last launch): fused yiq->rgb epilogue.
// ---------------------------------------------------------------------------
__global__ __launch_bounds__(256, 4)
void iter5p_kernel(const u32* __restrict__ xin, u32* __restrict__ xout,
                   const W8* __restrict__ w, const float* __restrict__ Ypad,
                   float* __restrict__ out, int writeRGB) {
    __shared__ __align__(16) u32 xsm[2][R * XSH];
    int tid = threadIdx.x;
    int gi0 = blockIdx.y * TILE - T;
    int gj0 = blockIdx.x * TILE - T;

    // stage x region (half2 px = b32 loads/stores)
#pragma unroll
    for (int k = 0; k < NK; ++k) {
        int pidx = tid + k * 256;
        if (pidx < NPX) {
            int r = pidx / R, c = pidx - r * R;
            xsm[0][r * XSH + c] = xin[(gi0 + r + PO) * PS + (gj0 + c + PO)];
        }
    }

    bool active = tid < 200;
    int s  = tid / 20;
    int cp = tid - s * 20;
    int r0 = 1 + 4 * s;        // output rows r0..r0+3 (in [1,40])
    int c0 = 1 + 2 * cp;       // output cols c0, c0+1 (c0-1 = 2cp even)

    // weights: load packed W8 for both patch pixels per row, duplicate each
    // fp16 weight into half2(w,w) for pk-fma. 64 u32 regs total.
    __half2 wL[4][8], wR[4][8];
    bool keepL[4], keepR[4];
    if (active) {
#pragma unroll
        for (int i = 0; i < 4; ++i) {
            int gp = (gi0 + r0 + i + PO) * PS + (gj0 + c0 + PO);
            W8 wa = w[gp];
            W8 wb = w[gp + 1];
            keepL[i] = (u2(wa.a) & 0x8000u) != 0u;
            keepR[i] = (u2(wb.a) & 0x8000u) != 0u;
            wL[i][0] = __low2half2(wa.a);  wL[i][1] = __high2half2(wa.a);
            wL[i][2] = __low2half2(wa.b);  wL[i][3] = __high2half2(wa.b);
            wL[i][4] = __low2half2(wa.c);  wL[i][5] = __high2half2(wa.c);
            wL[i][6] = __low2half2(wa.d);  wL[i][7] = __high2half2(wa.d);
            wR[i][0] = __low2half2(wb.a);  wR[i][1] = __high2half2(wb.a);
            wR[i][2] = __low2half2(wb.b);  wR[i][3] = __high2half2(wb.b);
            wR[i][4] = __low2half2(wb.c);  wR[i][5] = __high2half2(wb.c);
            wR[i][6] = __low2half2(wb.d);  wR[i][7] = __high2half2(wb.d);
        }
    }
    __syncthreads();

    const __half2 hz = __floats2half2_rn(0.f, 0.f);
    int cur = 0;
#pragma unroll
    for (int t = 1; t <= T; ++t) {
        int nxt = cur ^ 1;
        if (active) {
            // window rows as uint2 pairs: {px c0-1,c0} and {px c0+1,c0+2}
            const uint2* rp;
            uint2 u0, u1, m0, m1;
            rp = (const uint2*)&xsm[cur][(r0 - 1) * XSH]; u0 = rp[cp]; u1 = rp[cp + 1];
            rp = (const uint2*)&xsm[cur][r0 * XSH];       m0 = rp[cp]; m1 = rp[cp + 1];
#pragma unroll
            for (int i = 0; i < 4; ++i) {
                uint2 d0, d1;
                rp = (const uint2*)&xsm[cur][(r0 + i + 1) * XSH];
                d0 = rp[cp]; d1 = rp[cp + 1];

                // left pixel (r0+i, c0): nbrs UL,U,UR,L,R,DL,D,DR
                __half2 accL = keepL[i] ? h2(m0.y) : hz;
                accL = __hfma2(wL[i][0], h2(u0.x), accL);
                accL = __hfma2(wL[i][1], h2(u0.y), accL);
                accL = __hfma2(wL[i][2], h2(u1.x), accL);
                accL = __hfma2(wL[i][3], h2(m0.x), accL);
                accL = __hfma2(wL[i][4], h2(m1.x), accL);
                accL = __hfma2(wL[i][5], h2(d0.x), accL);
                accL = __hfma2(wL[i][6], h2(d0.y), accL);
                accL = __hfma2(wL[i][7], h2(d1.x), accL);

                // right pixel (r0+i, c0+1)
                __half2 accR = keepR[i] ? h2(m1.x) : hz;
                accR = __hfma2(wR[i][0], h2(u0.y), accR);
                accR = __hfma2(wR[i][1], h2(u1.x), accR);
                accR = __hfma2(wR[i][2], h2(u1.y), accR);
                accR = __hfma2(wR[i][3], h2(m0.y), accR);
                accR = __hfma2(wR[i][4], h2(m1.y), accR);
                accR = __hfma2(wR[i][5], h2(d0.y), accR);
                accR = __hfma2(wR[i][6], h2(d1.x), accR);
                accR = __hfma2(wR[i][7], h2(d1.y), accR);

                int wp = (r0 + i) * XSH + c0;
                xsm[nxt][wp]     = u2(accL);
                xsm[nxt][wp + 1] = u2(accR);

                u0 = m0; u1 = m1; m0 = d0; m1 = d1;  // slide window
            }
        }
        __syncthreads();
        cur = nxt;
    }

    if (!writeRGB) {
        // write central 32x32 tile (region rows/cols 5..36) as half2
#pragma unroll
        for (int k = 0; k < 4; ++k) {
            int pidx = tid + k * 256;
            int r = T + (pidx >> 5), c = T + (pidx & 31);
            xout[(gi0 + r + PO) * PS + (gj0 + c + PO)] = xsm[cur][r * XSH + c];
        }
    } else {
        // fused final: yiq -> rgb, clip, *255 straight from LDS
#pragma unroll
        for (int k = 0; k < 4; ++k) {
            int pidx = tid + k * 256;
            int r = T + (pidx >> 5), c = T + (pidx & 31);
            int gi = gi0 + r, gj = gj0 + c;
            float y = Ypad[(gi + PO) * PS + (gj + PO)];
            u32 pxv = xsm[cur][r * XSH + c];
            float2 iq = __half22float2(h2(pxv));
            float R_ = y + 0.9468822170900693f * iq.x + 0.6235565819861433f * iq.y;
            float G_ = y - 0.27478764629897834f * iq.x - 0.6356910791873801f * iq.y;
            float B_ = y - 1.1085450346420322f * iq.x + 1.7090069284064666f * iq.y;
            int idx = gi * Ww + gj;
            out[idx * 3 + 0] = fminf(fmaxf(R_, 0.f), 1.f) * 255.f;
            out[idx * 3 + 1] = fminf(fmaxf(G_, 0.f), 1.f) * 255.f;
            out[idx * 3 + 2] = fminf(fmaxf(B_, 0.f), 1.f) * 255.f;
        }
    }
}

extern "C" void kernel_launch(void* const* d_in, const int* in_sizes, int n_in,
                              void* d_out, int out_size, void* d_ws, size_t ws_size,
                              hipStream_t stream) {
    const float* gray = (const float*)d_in[0];
    const float* app  = (const float*)d_in[1];
    float* out = (float*)d_out;

    char* ws = (char*)d_ws;
    size_t off = 0;
    auto alloc = [&](size_t bytes) -> void* {
        void* r = ws + off;
        off = (off + bytes + 255) & ~(size_t)255;
        return r;
    };
    float* Ypad = (float*)alloc((size_t)PS * PS * sizeof(float));
    W8*    w    = (W8*)   alloc((size_t)PS * PS * sizeof(W8));
    unsigned char* mask = (unsigned char*)alloc((size_t)Hh * Ww);
    u32*   x0   = (u32*)  alloc((size_t)PS * PS * sizeof(u32));
    u32*   x1   = (u32*)  alloc((size_t)PS * PS * sizeof(u32));

    dim3 blk(64, 4);
    dim3 gridPad((PS + 63) / 64, (PS + 3) / 4);
    prep_kernel<<<gridPad, blk, 0, stream>>>(gray, app, Ypad, x0, x1, mask);
    weights_kernel<<<gridPad, blk, 0, stream>>>(Ypad, mask, w);

    dim3 gridIter(Ww / TILE, Hh / TILE);  // 32 x 32 = 1024 blocks
    u32* xin = x0;
    u32* xout = x1;
    for (int l = 0; l < 20; ++l) {        // 20 x 5 = 100 iterations
        int last = (l == 19) ? 1 : 0;
        iter5p_kernel<<<gridIter, 256, 0, stream>>>(xin, xout, w, Ypad, out, last);
        u32* tmp = xin; xin = xout; xout = tmp;
    }
}